// Round 2
// 208.447 us; speedup vs baseline: 1.0072x; 1.0072x over previous
//
#include <hip/hip_runtime.h>

typedef float fvec4 __attribute__((ext_vector_type(4)));

// out[t, :] = sum_k scores[t*K+k] * moe[slots[t*K+k], :]
//
// Fast path (top_k == 2, the benched shape): one block per token,
// one float4 per lane (16 B/lane coalescing sweet spot), both expert-row
// loads issued back-to-back, K fully unrolled, nontemporal stores so the
// 64 MB write-once output stream does not evict gathered rows from L2/L3
// (~37% of row reads are Poisson-collision re-reads that can cache-hit).
__global__ __launch_bounds__(512) void moe_gather_k2(
    const float* __restrict__ moe,     // [total_slots, hidden]
    const float* __restrict__ scores,  // [total_slots]
    const int*   __restrict__ slots,   // [total_slots]
    float*       __restrict__ out,     // [n_tokens, hidden]
    int hidden, int nvec) {
    const int t = blockIdx.x;
    // Wave-uniform scalar loads (t is uniform -> s_load path)
    const int   s0 = slots[2 * t + 0];
    const int   s1 = slots[2 * t + 1];
    const float w0 = scores[2 * t + 0];
    const float w1 = scores[2 * t + 1];
    const fvec4* __restrict__ r0 = (const fvec4*)(moe + (size_t)s0 * hidden);
    const fvec4* __restrict__ r1 = (const fvec4*)(moe + (size_t)s1 * hidden);
    fvec4* __restrict__ orow = (fvec4*)(out + (size_t)t * hidden);

    // nvec == blockDim.x for the benched shape (2048/4 = 512): single pass,
    // no loop bookkeeping. Loop kept for shape generality.
    for (int v = threadIdx.x; v < nvec; v += blockDim.x) {
        fvec4 a = r0[v];
        fvec4 b = r1[v];
        fvec4 acc = w0 * a + w1 * b;
        __builtin_nontemporal_store(acc, orow + v);
    }
}

// Generic fallback (any top_k <= 8): previous best kernel.
__global__ __launch_bounds__(256) void moe_gather_generic(
    const float* __restrict__ moe,
    const float* __restrict__ scores,
    const int*   __restrict__ slots,
    float*       __restrict__ out,
    int hidden, int top_k) {
    const int t   = blockIdx.x;
    const int tid = threadIdx.x;
    const int nvec = hidden >> 2;

    float w[8];
    const float4* rows[8];
    const int K = top_k > 8 ? 8 : top_k;
    for (int k = 0; k < K; ++k) {
        const int s = slots[(size_t)t * top_k + k];
        w[k] = scores[(size_t)t * top_k + k];
        rows[k] = (const float4*)(moe + (size_t)s * hidden);
    }

    float4* orow = (float4*)(out + (size_t)t * hidden);
    for (int v = tid; v < nvec; v += blockDim.x) {
        float4 acc = make_float4(0.f, 0.f, 0.f, 0.f);
        for (int k = 0; k < K; ++k) {
            float4 x = rows[k][v];
            acc.x += w[k] * x.x;
            acc.y += w[k] * x.y;
            acc.z += w[k] * x.z;
            acc.w += w[k] * x.w;
        }
        orow[v] = acc;
    }
}

extern "C" void kernel_launch(void* const* d_in, const int* in_sizes, int n_in,
                              void* d_out, int out_size, void* d_ws, size_t ws_size,
                              hipStream_t stream) {
    const float* moe    = (const float*)d_in[0];
    const float* scores = (const float*)d_in[1];
    const int*   slots  = (const int*)d_in[2];
    float* out = (float*)d_out;

    const int total_slots = in_sizes[1];                // 16384
    const int hidden      = in_sizes[0] / total_slots;  // 2048
    const int n_tokens    = out_size / hidden;          // 8192
    const int top_k       = total_slots / n_tokens;     // 2

    const int nvec = hidden >> 2;
    if (top_k == 2 && (hidden & 3) == 0 && nvec >= 64 && nvec <= 1024) {
        // 2048 -> 512 threads: exactly one float4 per lane.
        moe_gather_k2<<<n_tokens, nvec, 0, stream>>>(moe, scores, slots, out,
                                                     hidden, nvec);
    } else {
        moe_gather_generic<<<n_tokens, 256, 0, stream>>>(moe, scores, slots, out,
                                                         hidden, top_k);
    }
}